// Round 10
// baseline (718.656 us; speedup 1.0000x reference)
//
#include <hip/hip_runtime.h>
#include <hip/hip_bf16.h>

// Self-attention: context = softmax((X@Wq)(X@Wk)^T / sqrt(d)) @ X
// N=8192, d=1024, fp32. Near-one-hot scores => fp32-grade score accuracy:
// f16 split (hi+lo, 3-term Ootomo) MFMA GEMMs for projections and QK^T;
// plain f16 MFMA for P@V.
//
// R18: remove the self-inflicted LDS drain. R13-R17 forced
//      lgkmcnt(0)+sched_barrier(0) before each MFMA cluster, putting the
//      ~770 cyc/phase LDS service time on the critical path (R17's null
//      phase-halving falsified the fixed-overhead theory; the gap matches
//      LDS drain). Compiler loads get exact counted lgkm waits interleaved
//      with MFMAs when not blocked (m97 asm evidence) -> first MFMA starts
//      when its frags land, rest of the drain hides under the cluster.
//      Delta vs R17: lgkm(0)+sched_barrier(0) -> empty asm memory fence.
//      Safety unchanged: frag reads still sit after the vmcnt+barrier that
//      retire their rows (vmcnt asm "memory" clobber blocks hoisting).

typedef _Float16 f16x8 __attribute__((ext_vector_type(8)));
typedef float    f32x4 __attribute__((ext_vector_type(4)));

// async global->LDS, 16 B per lane; LDS dest = wave-uniform base + lane*16
__device__ __forceinline__ void g2lds16(const _Float16* g, _Float16* l) {
    __builtin_amdgcn_global_load_lds(
        (__attribute__((address_space(1))) unsigned int*)(g),
        (__attribute__((address_space(3))) unsigned int*)(l),
        16, 0, 0);
}

// ---------------------------------------------------------------- helpers

// one pass over X: write Xhi/Xlo (row-major split) and XT (f16 transpose)
__global__ void prep_x(const float* __restrict__ src,
                       _Float16* __restrict__ hi, _Float16* __restrict__ lo,
                       _Float16* __restrict__ xt, int R, int C) {
    __shared__ float tile[32][33];
    int c0 = blockIdx.x * 32, r0 = blockIdx.y * 32;
    int tx = threadIdx.x, ty = threadIdx.y;   // (32, 8)
#pragma unroll
    for (int k = 0; k < 4; ++k) {
        int r = ty + 8 * k;
        size_t idx = (size_t)(r0 + r) * C + c0 + tx;
        float v = src[idx];
        tile[r][tx] = v;
        _Float16 h = (_Float16)v;
        hi[idx] = h;
        lo[idx] = (_Float16)(v - (float)h);
    }
    __syncthreads();
#pragma unroll
    for (int k = 0; k < 4; ++k) {
        float v = tile[tx][ty + 8 * k];
        xt[(size_t)(c0 + ty + 8 * k) * R + r0 + tx] = (_Float16)v;
    }
}

// dst[c][r] = src[r][c] with f16 hi/lo split (weights)
__global__ void transpose_split(const float* __restrict__ src,
                                _Float16* __restrict__ dhi,
                                _Float16* __restrict__ dlo,
                                int R, int C) {
    __shared__ float tile[32][33];
    int c0 = blockIdx.x * 32, r0 = blockIdx.y * 32;
    int tx = threadIdx.x, ty = threadIdx.y;   // (32, 8)
#pragma unroll
    for (int k = 0; k < 4; ++k)
        tile[ty + 8 * k][tx] = src[(size_t)(r0 + ty + 8 * k) * C + c0 + tx];
    __syncthreads();
#pragma unroll
    for (int k = 0; k < 4; ++k) {
        float v = tile[tx][ty + 8 * k];
        _Float16 h = (_Float16)v;
        size_t idx = (size_t)(c0 + ty + 8 * k) * R + r0 + tx;
        dhi[idx] = h;
        dlo[idx] = (_Float16)(v - (float)h);
    }
}

// reduce 8 f16 split-K partials from the high granule of each 32KB row
// slot: partial(z,r,c) at halves offset r*16384 + 8192 + z*1024 + c.
__global__ __launch_bounds__(128) void add_gran(const _Float16* __restrict__ g,
                                                float* __restrict__ out) {
    const long r = blockIdx.x;
    const int t = threadIdx.x;          // 128 threads x 8 cols
    const _Float16* base = g + r * 16384 + 8192 + t * 8;
    float acc[8] = {0, 0, 0, 0, 0, 0, 0, 0};
#pragma unroll
    for (int z = 0; z < 8; ++z) {
        f16x8 v = *(const f16x8*)(base + z * 1024);
#pragma unroll
        for (int i = 0; i < 8; ++i) acc[i] += (float)v[i];
    }
    float4* o = (float4*)(out + r * 1024 + t * 8);
    o[0] = make_float4(acc[0], acc[1], acc[2], acc[3]);
    o[1] = make_float4(acc[4], acc[5], acc[6], acc[7]);
}

// ---------------------------------------------------------------- GEMM
// 256x256 tile, 512 threads (8 waves 2Mx4N), 2 phases per K-tile,
// double-buffered LDS (128 KiB), counted-vmcnt software pipeline,
// 16x16x32 f16 MFMA.
// C[M,N] fp32 = sum_k A[M,K] * B_bt[N,K]^T  (row-major; B in bt form).
// TERMS==3: A=Ahi+Alo, B=Bhi+Blo, hh+hl+lh (Ootomo), BKH=32.
// TERMS==1: plain f16, BKH=64.
// SPLIT_OUT: epilogue stores f16 hi/lo pair instead of fp32.
// GRAN: epilogue stores f16 split-K partial at Chi halves offset
//       row*16384 + 8192 + z*1024 + col (dead high granule of Sc rows).
// Phase P covers A-rows [P*64, P*64+64). Staging for tile t+1:
//   P0: B0..B3, A0, A1;  P1: A2, A3   (per-thread FIFO order).
// Counted waits (FIFO-traced): steady P0-end vmcnt(6), P1-end vmcnt(2);
// prologue vmcnt(2); last tile P0-end vmcnt(0).
// ONE barrier per phase; no trailing barrier; no manual lgkm drain --
// compiler emits counted lgkm interleaved with the MFMA cluster.
// MFMA cluster is TERM-OUTER: 16 independent hh, then 16 hl, then 16 lh.
template <int TERMS, int BKH, int SWAP, int SPLIT_OUT, int GRAN>
__global__ __launch_bounds__(512, 2) void gemm_p4(
    const _Float16* __restrict__ Ahi, const _Float16* __restrict__ Alo,
    const _Float16* __restrict__ Bhi, const _Float16* __restrict__ Blo,
    float* __restrict__ C, _Float16* __restrict__ Chi, _Float16* __restrict__ Clo,
    long lda, long ldb, long ldc, int K, int nrb, int ncb,
    long zA, long zB, long zC) {
    static_assert(BKH == 32 || BKH == 64, "");
    constexpr int NMAT = (TERMS == 3) ? 4 : 2;   // staged matrices
    constexpr int KK   = BKH / 32;               // MFMA k-steps per tile
    constexpr int LPR  = BKH / 8;                // threads per LDS row
    constexpr int MATH = 256 * BKH;              // halves per matrix buffer
    __shared__ __align__(16) _Float16 s[2][NMAT * MATH];   // 128 KiB

    const long z = blockIdx.z;
    Ahi += z * zA; Bhi += z * zB;
    if constexpr (TERMS == 3) { Alo += z * zA; Blo += z * zB; }
    if constexpr (SPLIT_OUT) { Chi += z * zC; Clo += z * zC; }
    else if constexpr (!GRAN) C += z * zC;

    // bijective XCD-chunked block swizzle (m204; works for any nb)
    const int nb = nrb * ncb;
    const int orig = blockIdx.x;
    const int q = nb >> 3, r8 = nb & 7;
    const int xcd = orig & 7, pos = orig >> 3;
    const int sw = (xcd < r8 ? xcd * (q + 1) : r8 * (q + 1) + (xcd - r8) * q) + pos;
    int rb, cb;
    if constexpr (SWAP) { rb = sw / ncb; cb = sw % ncb; }
    else                { cb = sw / nrb; rb = sw % nrb; }
    const long rowBase = (long)rb * 256;
    const long colBase = (long)cb * 256;

    const int t = threadIdx.x;
    const int wave = t >> 6;
    const int lane = t & 63;
    const int lm = lane & 15;     // row/col within 16-tile
    const int lq = lane >> 4;     // quad 0..3
    const int wr = wave >> 2;     // wave row 0..1  (rows wr*128 .. +127)
    const int wc = wave & 3;      // wave col 0..3  (cols wc*64 .. +63)
    const int wg = wave & 3;      // wave index within its A-group

    // ---- staging addressing (pre-swizzled source, linear LDS dest) ----
    const int ri   = lane / LPR;              // row within wave chunk
    const int slot = lane % LPR;              // 16B column slot
    const int swzW = (BKH == 32) ? ((ri >> 1) & 3) : (ri & 7);
    const int colOff = (slot ^ swzW) * 8;     // pre-swizzled source column

    // per-issue source pointers (per-lane) and LDS bases (wave-uniform)
    const _Float16* gB[4]; int lB[4];
    const _Float16* gA[4]; int lA[4];
#pragma unroll
    for (int b = 0; b < 4; ++b) {
        if constexpr (TERMS == 3) {
            const int rowW = (b >> 1) * 128 + wave * 16;       // hi/lo pairs
            const _Float16* m = (b & 1) ? Blo : Bhi;
            gB[b] = m + (colBase + rowW + ri) * ldb + colOff;
            lB[b] = (2 + (b & 1)) * MATH + rowW * BKH;
        } else {
            const int rowW = b * 64 + wave * 8;
            gB[b] = Bhi + (colBase + rowW + ri) * ldb + colOff;
            lB[b] = MATH + rowW * BKH;
        }
    }
#pragma unroll
    for (int a = 0; a < 4; ++a) {
        if constexpr (TERMS == 3) {
            // group wr stages its half; j=a>>1 covers rows [64j,64j+64)
            const int rowW = wr * 128 + (a >> 1) * 64 + wg * 16;
            const _Float16* m = (a & 1) ? Alo : Ahi;
            gA[a] = m + (rowBase + rowW + ri) * lda + colOff;
            lA[a] = (a & 1) * MATH + rowW * BKH;
        } else {
            // issue a covers rows [32a, 32a+32) of the group's half
            const int rowW = wr * 128 + a * 32 + wg * 8;
            gA[a] = Ahi + (rowBase + rowW + ri) * lda + colOff;
            lA[a] = rowW * BKH;
        }
    }

    // reader-side swizzle (row bits used come from lm / ri consistently)
    const int swzR = (BKH == 32) ? ((lm >> 1) & 3) : (lm & 7);

    f32x4 acc[8][4];
#pragma unroll
    for (int rr = 0; rr < 8; ++rr)
#pragma unroll
        for (int cc = 0; cc < 4; ++cc)
#pragma unroll
            for (int i = 0; i < 4; ++i) acc[rr][cc][i] = 0.0f;

    const int NT = K / BKH;

#define VMW(N) asm volatile("s_waitcnt vmcnt(" #N ")" ::: "memory")
#define STB(b, buf, k0) g2lds16(gB[b] + (k0), &s[buf][lB[b]])
#define STA(a, buf, k0) g2lds16(gA[a] + (k0), &s[buf][lA[a]])

    // prologue: tile 0 -> buf 0, issue order matches steady state;
    // retire what P0 reads (B, A0, A1 = 6 oldest) before first ds_read.
    STB(0, 0, 0); STB(1, 0, 0); STB(2, 0, 0); STB(3, 0, 0);
    STA(0, 0, 0); STA(1, 0, 0); STA(2, 0, 0); STA(3, 0, 0);
    VMW(2);
    __builtin_amdgcn_s_barrier();

    int cur = 0;
    for (int tt = 0; tt < NT; ++tt) {
        const int nxt = cur ^ 1;
        const bool nl = (tt + 1 < NT);
        const long k1 = (long)(tt + 1) * BKH;
        const _Float16* sAh = &s[cur][0];
        const _Float16* sAl = sAh + MATH;                          // TERMS==3
        const _Float16* sBh = sAh + (TERMS == 3 ? 2 : 1) * MATH;
        const _Float16* sBl = sAh + 3 * MATH;                      // TERMS==3
        f16x8 bh[4 * KK], bl[TERMS == 3 ? 4 * KK : 1];
#pragma unroll
        for (int p = 0; p < 2; ++p) {
            // ---- ds_read this phase's A rows [p*64, p*64+64) ----
            f16x8 ah[4 * KK], al[TERMS == 3 ? 4 * KK : 1];
#pragma unroll
            for (int rr = 0; rr < 4; ++rr) {
                const int arow = wr * 128 + (4 * p + rr) * 16 + lm;
#pragma unroll
                for (int kk = 0; kk < KK; ++kk) {
                    const int off = arow * BKH + (((kk * 4 + lq) ^ swzR) << 3);
                    ah[rr * KK + kk] = *(const f16x8*)&sAh[off];
                    if constexpr (TERMS == 3)
                        al[rr * KK + kk] = *(const f16x8*)&sAl[off];
                }
            }
            if (p == 0) {
#pragma unroll
                for (int cc = 0; cc < 4; ++cc) {
                    const int brow = wc * 64 + cc * 16 + lm;
#pragma unroll
                    for (int kk = 0; kk < KK; ++kk) {
                        const int off = brow * BKH + (((kk * 4 + lq) ^ swzR) << 3);
                        bh[cc * KK + kk] = *(const f16x8*)&sBh[off];
                        if constexpr (TERMS == 3)
                            bl[cc * KK + kk] = *(const f16x8*)&sBl[off];
                    }
                }
            }
            // ---- stage portion p of tile tt+1 into buf nxt ----
            if (nl) {
                if (p == 0) { STB(0, nxt, k1); STB(1, nxt, k1);
                              STB(2, nxt, k1); STB(3, nxt, k1);
                              STA(0, nxt, k1); STA(1, nxt, k1); }
                else        { STA(2, nxt, k1); STA(3, nxt, k1); }
            }
            // ---- counted wait: retire exactly what the NEXT phase reads.
            // FIFO: P0-end queue = [A2,A3 | B0..B3,A0,A1] -> vmcnt(6)
            //       P1-end queue = [B0..B3,A0,A1 | A2,A3] -> vmcnt(2)
            // last tile: P0-end [A2,A3] -> vmcnt(0); P1-end none.
            if (p == 0) { if (nl) { VMW(6); } else { VMW(0); } }
            else        { if (nl) { VMW(2); } }
            __builtin_amdgcn_s_barrier();
            asm volatile("" ::: "memory");   // IR fence only; no lgkm drain:
            // compiler emits counted lgkm interleaved with the cluster, so
            // the LDS drain (~770 cyc/phase) hides under MFMA issue.
            __builtin_amdgcn_s_setprio(1);
            // term-outer: 16 independent hh, then 16 hl, then 16 lh (per-acc
            // accumulation order unchanged: hh, hl, lh)
#pragma unroll
            for (int rr = 0; rr < 4; ++rr)
#pragma unroll
                for (int cc = 0; cc < 4; ++cc)
#pragma unroll
                    for (int kk = 0; kk < KK; ++kk)
                        acc[4 * p + rr][cc] = __builtin_amdgcn_mfma_f32_16x16x32_f16(
                            ah[rr * KK + kk], bh[cc * KK + kk], acc[4 * p + rr][cc], 0, 0, 0);
            if constexpr (TERMS == 3) {
#pragma unroll
                for (int rr = 0; rr < 4; ++rr)
#pragma unroll
                    for (int cc = 0; cc < 4; ++cc)
#pragma unroll
                        for (int kk = 0; kk < KK; ++kk)
                            acc[4 * p + rr][cc] = __builtin_amdgcn_mfma_f32_16x16x32_f16(
                                ah[rr * KK + kk], bl[cc * KK + kk], acc[4 * p + rr][cc], 0, 0, 0);
#pragma unroll
                for (int rr = 0; rr < 4; ++rr)
#pragma unroll
                    for (int cc = 0; cc < 4; ++cc)
#pragma unroll
                        for (int kk = 0; kk < KK; ++kk)
                            acc[4 * p + rr][cc] = __builtin_amdgcn_mfma_f32_16x16x32_f16(
                                al[rr * KK + kk], bh[cc * KK + kk], acc[4 * p + rr][cc], 0, 0, 0);
            }
            __builtin_amdgcn_s_setprio(0);
            // no trailing barrier: next phase's ds_reads overlap other
            // waves' MFMA (max skew one phase; hazards barriered above)
        }
        cur = nxt;
    }
#undef VMW
#undef STB
#undef STA

    // C/D layout: col = lane&15, row = quad*4 + reg  (verified m89/m91)
#pragma unroll
    for (int rr = 0; rr < 8; ++rr)
#pragma unroll
        for (int cc = 0; cc < 4; ++cc)
#pragma unroll
            for (int i = 0; i < 4; ++i) {
                const long row = rowBase + wr * 128 + rr * 16 + lq * 4 + i;
                const long col = colBase + wc * 64 + cc * 16 + lm;
                if constexpr (GRAN) {
                    // f16 partial into dead high granule of this row's slot
                    Chi[row * 16384 + 8192 + z * 1024 + col] =
                        (_Float16)acc[rr][cc][i];
                } else if constexpr (SPLIT_OUT) {
                    float v = acc[rr][cc][i];
                    _Float16 h = (_Float16)v;
                    Chi[row * ldc + col] = h;
                    Clo[row * ldc + col] = (_Float16)(v - (float)h);
                } else {
                    C[row * ldc + col] = acc[rr][cc][i];
                }
            }
}

// ---------------------------------------------------------------- softmax
// One block per row (8192 fp32). Whole row into registers (paired float4 =
// 32 B/lane contiguous), reduce max and sum(exp), write P f16 as 16 B
// chunks (aliases the fp32 row in-place: all reads complete before the
// first barrier, writes after the last). Scale 1/32 folded in.
__global__ __launch_bounds__(256) void softmax_rows(const float* __restrict__ S,
                                                    _Float16* __restrict__ P,
                                                    long ldp, int N) {
    const int row = blockIdx.x;
    const int t = threadIdx.x;
    const float4* rowp = (const float4*)(S + (size_t)row * N);
    float4 v[8];
    float mx = -3.4e38f;
#pragma unroll
    for (int g = 0; g < 4; ++g) {
        v[2 * g]     = rowp[2 * t + 512 * g];
        v[2 * g + 1] = rowp[2 * t + 512 * g + 1];
    }
#pragma unroll
    for (int i = 0; i < 8; ++i)
        mx = fmaxf(mx, fmaxf(fmaxf(v[i].x, v[i].y), fmaxf(v[i].z, v[i].w)));
    __shared__ float red[8];
#pragma unroll
    for (int off = 32; off >= 1; off >>= 1) mx = fmaxf(mx, __shfl_xor(mx, off));
    if ((t & 63) == 0) red[t >> 6] = mx;
    __syncthreads();
    mx = fmaxf(fmaxf(red[0], red[1]), fmaxf(red[2], red[3]));

    float sum = 0.0f;
#pragma unroll
    for (int i = 0; i < 8; ++i) {
        v[i].x = __expf((v[i].x - mx) * 0.03125f);
        v[i].y = __expf((v[i].y - mx) * 0.03125f);
        v[i].z = __expf((v[i].z - mx) * 0.03125f);
        v[i].w = __expf((v[i].w - mx) * 0.03125f);
        sum += (v[i].x + v[i].y) + (v[i].z + v[i].w);
    }
#pragma unroll
    for (int off = 32; off >= 1; off >>= 1) sum += __shfl_xor(sum, off);
    if ((t & 63) == 0) red[4 + (t >> 6)] = sum;
    __syncthreads();
    float inv = 1.0f / (red[4] + red[5] + red[6] + red[7]);

    f16x8* prow = (f16x8*)(P + (size_t)row * ldp);
#pragma unroll
    for (int g = 0; g < 4; ++g) {
        float4 a = v[2 * g], b = v[2 * g + 1];
        f16x8 o;
        o[0] = (_Float16)(a.x * inv); o[1] = (_Float16)(a.y * inv);
        o[2] = (_Float16)(a.z * inv); o[3] = (_Float16)(a.w * inv);
        o[4] = (_Float16)(b.x * inv); o[5] = (_Float16)(b.y * inv);
        o[6] = (_Float16)(b.z * inv); o[7] = (_Float16)(b.w * inv);
        prow[t + 256 * g] = o;
    }
}

// ---------------------------------------------------------------- launch
extern "C" void kernel_launch(void* const* d_in, const int* in_sizes, int n_in,
                              void* d_out, int out_size, void* d_ws, size_t ws_size,
                              hipStream_t stream) {
    const float* X  = (const float*)d_in[0];  // [8192,1024]
    const float* Wq = (const float*)d_in[1];  // [1024,1024]
    const float* Wk = (const float*)d_in[2];  // [1024,1024]
    float* out = (float*)d_out;               // [8192,1024]

    const long Nt = 8192, D = 1024;
    char* ws = (char*)d_ws;
    const size_t MB = 1024ull * 1024ull;

    // Persistent region (80 MB):
    _Float16* XT  = (_Float16*)(ws + 0);        // 16 MB [1024][8192] = X^T f16
    _Float16* Qhi = (_Float16*)(ws + 16 * MB);  // 16 MB
    _Float16* Qlo = (_Float16*)(ws + 32 * MB);
    _Float16* Khi = (_Float16*)(ws + 48 * MB);
    _Float16* Klo = (_Float16*)(ws + 64 * MB);
    // Transient (dead after projections; Sc aliases them):
    _Float16* Xhi   = (_Float16*)(ws + 80 * MB);   // 16 MB
    _Float16* Xlo   = (_Float16*)(ws + 96 * MB);   // 16 MB
    _Float16* WqThi = (_Float16*)(ws + 112 * MB);  // 2 MB each, Wq/Wk adjacent
    _Float16* WqTlo = (_Float16*)(ws + 114 * MB);
    _Float16* WkThi = (_Float16*)(ws + 116 * MB);
    _Float16* WkTlo = (_Float16*)(ws + 118 * MB);

    // Chunk scratch: S fp32 rows (32 KB each). After softmax, each row slot
    // = [P f16 16 KB][dead 16 KB used for PV split-K f16 partials].
    const size_t rowBytes = (size_t)Nt * 4;  // 32 KB per S row
    float* Sc = (float*)(ws + 80 * MB);
    size_t avail = ws_size > 80 * MB ? ws_size - 80 * MB : 0;
    long chunk = (long)((avail / rowBytes / 256) * 256);
    if (chunk < 256) chunk = 256;   // smaller ws cannot work anyway
    if (chunk > Nt) chunk = Nt;
    // even-size chunks (avoid a tiny low-occupancy tail chunk)
    {
        long nch = (Nt + chunk - 1) / chunk;
        chunk = (((Nt + nch - 1) / nch) + 255) / 256 * 256;
    }

    // 1. prep: one pass over X -> Xhi,Xlo,XT; transpose+split weights
    prep_x<<<dim3(32, 256), dim3(32, 8), 0, stream>>>(X, Xhi, Xlo, XT,
                                                      (int)Nt, (int)D);
    transpose_split<<<dim3(32, 32), dim3(32, 8), 0, stream>>>(Wq, WqThi, WqTlo,
                                                              (int)D, (int)D);
    transpose_split<<<dim3(32, 32), dim3(32, 8), 0, stream>>>(Wk, WkThi, WkTlo,
                                                              (int)D, (int)D);

    // 2. fused Q+K projections (3-term split), z=0 -> Q, z=1 -> K.
    //    grid 32x4x2 = 256 blocks: exactly 1/CU.
    gemm_p4<3, 32, 1, 1, 0><<<dim3(32 * 4, 1, 2), 512, 0, stream>>>(
        Xhi, Xlo, WqThi, WqTlo, nullptr, Qhi, Qlo,
        D, D, D, (int)D, 32, 4,
        0, (long)(4 * MB / 2), (long)(32 * MB / 2));

    // 3. chunks: S = Q@K^T (3-term, fp32) -> softmax in place (P f16 in
    //    low granules) -> PV split-K=8 full-chip (f16 partials in high
    //    granules) -> add_gran reduce into out.
    long done = 0;
    while (done < Nt) {
        long cur = Nt - done < chunk ? Nt - done : chunk;
        int nrb = (int)(cur / 256), ncb = (int)(Nt / 256);
        gemm_p4<3, 32, 1, 0, 0><<<dim3(nrb * ncb, 1, 1), 512, 0, stream>>>(
            Qhi + done * D, Qlo + done * D, Khi, Klo, Sc, nullptr, nullptr,
            D, D, Nt, (int)D, nrb, ncb, 0, 0, 0);
        softmax_rows<<<(int)cur, 256, 0, stream>>>(Sc, (_Float16*)Sc,
                                                   2 * Nt, (int)Nt);
        // PV: A = P (sparse rows, lda = 2*Nt halves), B = XT, split-K=8
        // (z offsets k by 1024 in both A cols and XT cols). Grid
        // (cur/256) x 4 x 8 -> full chip.
        gemm_p4<1, 64, 1, 0, 1><<<dim3(nrb * 4, 1, 8), 512, 0, stream>>>(
            (const _Float16*)Sc, nullptr, XT, nullptr,
            nullptr, (_Float16*)Sc, nullptr,
            2 * Nt, Nt, D, (int)(Nt / 8), nrb, 4,
            Nt / 8, Nt / 8, 0);
        add_gran<<<(int)cur, 128, 0, stream>>>((const _Float16*)Sc,
                                               out + done * D);
        done += cur;
    }
}

// Round 11
// 708.982 us; speedup vs baseline: 1.0136x; 1.0136x over previous
//
#include <hip/hip_runtime.h>
#include <hip/hip_bf16.h>

// Self-attention: context = softmax((X@Wq)(X@Wk)^T / sqrt(d)) @ X
// N=8192, d=1024, fp32. Near-one-hot scores => fp32-grade score accuracy:
// f16 split (hi+lo, 3-term Ootomo) MFMA GEMMs for projections and QK^T;
// plain f16 MFMA for P@V.
//
// R19: revert to R16 core exactly (best measured: 711 us; R17 2-phase null,
//      R18 drain-removal regressed). ONE delta: S-GEMM grid mapping flips
//      SWAP=1 -> SWAP=0. Mechanism: SWAP=1 makes an XCD's 32 concurrent
//      blocks hold 32 DIFFERENT K panels (64 MB live vs 4 MB L2 -> thrash;
//      FETCH 270 MB vs 64 MB compulsory). SWAP=0 shares ~2 B panels
//      (4 MB = L2) among concurrent blocks; A streams via L3. PV keeps
//      SWAP=1 (R9 showed PV SWAP=0 thrashes). Discriminating counter:
//      S-GEMM FETCH_SIZE.

typedef _Float16 f16x8 __attribute__((ext_vector_type(8)));
typedef float    f32x4 __attribute__((ext_vector_type(4)));

// async global->LDS, 16 B per lane; LDS dest = wave-uniform base + lane*16
__device__ __forceinline__ void g2lds16(const _Float16* g, _Float16* l) {
    __builtin_amdgcn_global_load_lds(
        (__attribute__((address_space(1))) unsigned int*)(g),
        (__attribute__((address_space(3))) unsigned int*)(l),
        16, 0, 0);
}

// ---------------------------------------------------------------- helpers

// one pass over X: write Xhi/Xlo (row-major split) and XT (f16 transpose)
__global__ void prep_x(const float* __restrict__ src,
                       _Float16* __restrict__ hi, _Float16* __restrict__ lo,
                       _Float16* __restrict__ xt, int R, int C) {
    __shared__ float tile[32][33];
    int c0 = blockIdx.x * 32, r0 = blockIdx.y * 32;
    int tx = threadIdx.x, ty = threadIdx.y;   // (32, 8)
#pragma unroll
    for (int k = 0; k < 4; ++k) {
        int r = ty + 8 * k;
        size_t idx = (size_t)(r0 + r) * C + c0 + tx;
        float v = src[idx];
        tile[r][tx] = v;
        _Float16 h = (_Float16)v;
        hi[idx] = h;
        lo[idx] = (_Float16)(v - (float)h);
    }
    __syncthreads();
#pragma unroll
    for (int k = 0; k < 4; ++k) {
        float v = tile[tx][ty + 8 * k];
        xt[(size_t)(c0 + ty + 8 * k) * R + r0 + tx] = (_Float16)v;
    }
}

// dst[c][r] = src[r][c] with f16 hi/lo split (weights)
__global__ void transpose_split(const float* __restrict__ src,
                                _Float16* __restrict__ dhi,
                                _Float16* __restrict__ dlo,
                                int R, int C) {
    __shared__ float tile[32][33];
    int c0 = blockIdx.x * 32, r0 = blockIdx.y * 32;
    int tx = threadIdx.x, ty = threadIdx.y;   // (32, 8)
#pragma unroll
    for (int k = 0; k < 4; ++k)
        tile[ty + 8 * k][tx] = src[(size_t)(r0 + ty + 8 * k) * C + c0 + tx];
    __syncthreads();
#pragma unroll
    for (int k = 0; k < 4; ++k) {
        float v = tile[tx][ty + 8 * k];
        _Float16 h = (_Float16)v;
        size_t idx = (size_t)(c0 + ty + 8 * k) * R + r0 + tx;
        dhi[idx] = h;
        dlo[idx] = (_Float16)(v - (float)h);
    }
}

// reduce 8 f16 split-K partials from the high granule of each 32KB row
// slot: partial(z,r,c) at halves offset r*16384 + 8192 + z*1024 + c.
__global__ __launch_bounds__(128) void add_gran(const _Float16* __restrict__ g,
                                                float* __restrict__ out) {
    const long r = blockIdx.x;
    const int t = threadIdx.x;          // 128 threads x 8 cols
    const _Float16* base = g + r * 16384 + 8192 + t * 8;
    float acc[8] = {0, 0, 0, 0, 0, 0, 0, 0};
#pragma unroll
    for (int z = 0; z < 8; ++z) {
        f16x8 v = *(const f16x8*)(base + z * 1024);
#pragma unroll
        for (int i = 0; i < 8; ++i) acc[i] += (float)v[i];
    }
    float4* o = (float4*)(out + r * 1024 + t * 8);
    o[0] = make_float4(acc[0], acc[1], acc[2], acc[3]);
    o[1] = make_float4(acc[4], acc[5], acc[6], acc[7]);
}

// ---------------------------------------------------------------- GEMM
// 256x256 tile, 512 threads (8 waves 2Mx4N), 4 phases per K-tile,
// double-buffered LDS (128 KiB), counted-vmcnt software pipeline,
// 16x16x32 f16 MFMA.
// C[M,N] fp32 = sum_k A[M,K] * B_bt[N,K]^T  (row-major; B in bt form).
// TERMS==3: A=Ahi+Alo, B=Bhi+Blo, hh+hl+lh (Ootomo), BKH=32.
// TERMS==1: plain f16, BKH=64.
// SPLIT_OUT: epilogue stores f16 hi/lo pair instead of fp32.
// GRAN: epilogue stores f16 split-K partial at Chi halves offset
//       row*16384 + 8192 + z*1024 + col (dead high granule of Sc rows).
// Staging (R11/R13): per-thread issue order [B0..B3,A0..A3] for tile t+1,
// placed p0: Bx4; p1: A0,A1; p2: A2; p3: A3. Counted waits (FIFO-traced):
//   T3: p1-end vmcnt(5), p3-end vmcnt(2); last tile p1->0.
//   T1: p0->6, p1->6, p2->7, p3->3; last 2,1,0,-.
// ONE barrier per phase (after vmcnt, before lgkm+MFMA); no trailing
// barrier -> cross-wave read/MFMA overlap, max skew 1 phase.
// MFMA cluster is TERM-OUTER: 8 independent hh, then 8 hl, then 8 lh.
template <int TERMS, int BKH, int SWAP, int SPLIT_OUT, int GRAN>
__global__ __launch_bounds__(512, 2) void gemm_p4(
    const _Float16* __restrict__ Ahi, const _Float16* __restrict__ Alo,
    const _Float16* __restrict__ Bhi, const _Float16* __restrict__ Blo,
    float* __restrict__ C, _Float16* __restrict__ Chi, _Float16* __restrict__ Clo,
    long lda, long ldb, long ldc, int K, int nrb, int ncb,
    long zA, long zB, long zC) {
    static_assert(BKH == 32 || BKH == 64, "");
    constexpr int NMAT = (TERMS == 3) ? 4 : 2;   // staged matrices
    constexpr int KK   = BKH / 32;               // MFMA k-steps per tile
    constexpr int LPR  = BKH / 8;                // threads per LDS row
    constexpr int MATH = 256 * BKH;              // halves per matrix buffer
    __shared__ __align__(16) _Float16 s[2][NMAT * MATH];   // 128 KiB

    const long z = blockIdx.z;
    Ahi += z * zA; Bhi += z * zB;
    if constexpr (TERMS == 3) { Alo += z * zA; Blo += z * zB; }
    if constexpr (SPLIT_OUT) { Chi += z * zC; Clo += z * zC; }
    else if constexpr (!GRAN) C += z * zC;

    // bijective XCD-chunked block swizzle (m204; works for any nb)
    const int nb = nrb * ncb;
    const int orig = blockIdx.x;
    const int q = nb >> 3, r8 = nb & 7;
    const int xcd = orig & 7, pos = orig >> 3;
    const int sw = (xcd < r8 ? xcd * (q + 1) : r8 * (q + 1) + (xcd - r8) * q) + pos;
    int rb, cb;
    if constexpr (SWAP) { rb = sw / ncb; cb = sw % ncb; }
    else                { cb = sw / nrb; rb = sw % nrb; }
    const long rowBase = (long)rb * 256;
    const long colBase = (long)cb * 256;

    const int t = threadIdx.x;
    const int wave = t >> 6;
    const int lane = t & 63;
    const int lm = lane & 15;     // row/col within 16-tile
    const int lq = lane >> 4;     // quad 0..3
    const int wr = wave >> 2;     // wave row 0..1  (rows wr*128 .. +127)
    const int wc = wave & 3;      // wave col 0..3  (cols wc*64 .. +63)
    const int wg = wave & 3;      // wave index within its A-group

    // ---- staging addressing (pre-swizzled source, linear LDS dest) ----
    const int ri   = lane / LPR;              // row within wave chunk
    const int slot = lane % LPR;              // 16B column slot
    const int swzW = (BKH == 32) ? ((ri >> 1) & 3) : (ri & 7);
    const int colOff = (slot ^ swzW) * 8;     // pre-swizzled source column

    // per-issue source pointers (per-lane) and LDS bases (wave-uniform)
    const _Float16* gB[4]; int lB[4];
    const _Float16* gA[4]; int lA[4];
#pragma unroll
    for (int b = 0; b < 4; ++b) {
        if constexpr (TERMS == 3) {
            const int rowW = (b >> 1) * 128 + wave * 16;       // hi/lo pairs
            const _Float16* m = (b & 1) ? Blo : Bhi;
            gB[b] = m + (colBase + rowW + ri) * ldb + colOff;
            lB[b] = (2 + (b & 1)) * MATH + rowW * BKH;
        } else {
            const int rowW = b * 64 + wave * 8;
            gB[b] = Bhi + (colBase + rowW + ri) * ldb + colOff;
            lB[b] = MATH + rowW * BKH;
        }
    }
#pragma unroll
    for (int a = 0; a < 4; ++a) {
        if constexpr (TERMS == 3) {
            // group wr stages its half; j=a>>1 covers rows [64j,64j+64)
            const int rowW = wr * 128 + (a >> 1) * 64 + wg * 16;
            const _Float16* m = (a & 1) ? Alo : Ahi;
            gA[a] = m + (rowBase + rowW + ri) * lda + colOff;
            lA[a] = (a & 1) * MATH + rowW * BKH;
        } else {
            // issue a covers rows [32a, 32a+32) of the group's half
            const int rowW = wr * 128 + a * 32 + wg * 8;
            gA[a] = Ahi + (rowBase + rowW + ri) * lda + colOff;
            lA[a] = rowW * BKH;
        }
    }

    // reader-side swizzle (row bits used come from lm / ri consistently)
    const int swzR = (BKH == 32) ? ((lm >> 1) & 3) : (lm & 7);

    f32x4 acc[8][4];
#pragma unroll
    for (int rr = 0; rr < 8; ++rr)
#pragma unroll
        for (int cc = 0; cc < 4; ++cc)
#pragma unroll
            for (int i = 0; i < 4; ++i) acc[rr][cc][i] = 0.0f;

    const int NT = K / BKH;

#define VMW(N) asm volatile("s_waitcnt vmcnt(" #N ")" ::: "memory")
#define STB(b, buf, k0) g2lds16(gB[b] + (k0), &s[buf][lB[b]])
#define STA(a, buf, k0) g2lds16(gA[a] + (k0), &s[buf][lA[a]])

    // prologue: tile 0 -> buf 0, issue order matches steady state;
    // retire what p0 reads before the first ds_read.
    STB(0, 0, 0); STB(1, 0, 0); STB(2, 0, 0); STB(3, 0, 0);
    STA(0, 0, 0); STA(1, 0, 0); STA(2, 0, 0); STA(3, 0, 0);
    if constexpr (TERMS == 3) { VMW(2); } else { VMW(3); }
    __builtin_amdgcn_s_barrier();

    int cur = 0;
    for (int tt = 0; tt < NT; ++tt) {
        const int nxt = cur ^ 1;
        const bool nl = (tt + 1 < NT);
        const long k1 = (long)(tt + 1) * BKH;
        const _Float16* sAh = &s[cur][0];
        const _Float16* sAl = sAh + MATH;                          // TERMS==3
        const _Float16* sBh = sAh + (TERMS == 3 ? 2 : 1) * MATH;
        const _Float16* sBl = sAh + 3 * MATH;                      // TERMS==3
        f16x8 bh[4 * KK], bl[TERMS == 3 ? 4 * KK : 1];
#pragma unroll
        for (int p = 0; p < 4; ++p) {
            // ---- ds_read this phase's A rows (+ all B at p0) ----
            f16x8 ah[2 * KK], al[TERMS == 3 ? 2 * KK : 1];
#pragma unroll
            for (int rr = 0; rr < 2; ++rr) {
                const int arow = wr * 128 + (2 * p + rr) * 16 + lm;
#pragma unroll
                for (int kk = 0; kk < KK; ++kk) {
                    const int off = arow * BKH + (((kk * 4 + lq) ^ swzR) << 3);
                    ah[rr * KK + kk] = *(const f16x8*)&sAh[off];
                    if constexpr (TERMS == 3)
                        al[rr * KK + kk] = *(const f16x8*)&sAl[off];
                }
            }
            if (p == 0) {
#pragma unroll
                for (int cc = 0; cc < 4; ++cc) {
                    const int brow = wc * 64 + cc * 16 + lm;
#pragma unroll
                    for (int kk = 0; kk < KK; ++kk) {
                        const int off = brow * BKH + (((kk * 4 + lq) ^ swzR) << 3);
                        bh[cc * KK + kk] = *(const f16x8*)&sBh[off];
                        if constexpr (TERMS == 3)
                            bl[cc * KK + kk] = *(const f16x8*)&sBl[off];
                    }
                }
            }
            // ---- stage portion p of tile tt+1 into buf nxt (R11) ----
            if (nl) {
                if (p == 0)      { STB(0, nxt, k1); STB(1, nxt, k1);
                                   STB(2, nxt, k1); STB(3, nxt, k1); }
                else if (p == 1) { STA(0, nxt, k1); STA(1, nxt, k1); }
                else if (p == 2) { STA(2, nxt, k1); }
                else             { STA(3, nxt, k1); }
            }
            // ---- counted wait: retire exactly what the NEXT phase reads
            if constexpr (TERMS == 3) {
                if (p == 1)      { if (nl) { VMW(5); } else { VMW(0); } }
                else if (p == 3) { if (nl) { VMW(2); } }
            } else {
                if (p == 0)      { if (nl) { VMW(6); } else { VMW(2); } }
                else if (p == 1) { if (nl) { VMW(6); } else { VMW(1); } }
                else if (p == 2) { if (nl) { VMW(7); } else { VMW(0); } }
                else             { if (nl) { VMW(3); } }
            }
            __builtin_amdgcn_s_barrier();
            asm volatile("s_waitcnt lgkmcnt(0)" ::: "memory");
            __builtin_amdgcn_sched_barrier(0);
            __builtin_amdgcn_s_setprio(1);
            // term-outer: 8 independent hh, then 8 hl, then 8 lh (per-acc
            // accumulation order unchanged: hh, hl, lh)
#pragma unroll
            for (int rr = 0; rr < 2; ++rr)
#pragma unroll
                for (int cc = 0; cc < 4; ++cc)
#pragma unroll
                    for (int kk = 0; kk < KK; ++kk)
                        acc[2 * p + rr][cc] = __builtin_amdgcn_mfma_f32_16x16x32_f16(
                            ah[rr * KK + kk], bh[cc * KK + kk], acc[2 * p + rr][cc], 0, 0, 0);
            if constexpr (TERMS == 3) {
#pragma unroll
                for (int rr = 0; rr < 2; ++rr)
#pragma unroll
                    for (int cc = 0; cc < 4; ++cc)
#pragma unroll
                        for (int kk = 0; kk < KK; ++kk)
                            acc[2 * p + rr][cc] = __builtin_amdgcn_mfma_f32_16x16x32_f16(
                                ah[rr * KK + kk], bl[cc * KK + kk], acc[2 * p + rr][cc], 0, 0, 0);
#pragma unroll
                for (int rr = 0; rr < 2; ++rr)
#pragma unroll
                    for (int cc = 0; cc < 4; ++cc)
#pragma unroll
                        for (int kk = 0; kk < KK; ++kk)
                            acc[2 * p + rr][cc] = __builtin_amdgcn_mfma_f32_16x16x32_f16(
                                al[rr * KK + kk], bh[cc * KK + kk], acc[2 * p + rr][cc], 0, 0, 0);
            }
            __builtin_amdgcn_s_setprio(0);
            // no trailing barrier: next phase's ds_reads overlap other
            // waves' MFMA (max skew one phase; hazards barriered above)
        }
        cur = nxt;
    }
#undef VMW
#undef STB
#undef STA

    // C/D layout: col = lane&15, row = quad*4 + reg  (verified m89/m91)
#pragma unroll
    for (int rr = 0; rr < 8; ++rr)
#pragma unroll
        for (int cc = 0; cc < 4; ++cc)
#pragma unroll
            for (int i = 0; i < 4; ++i) {
                const long row = rowBase + wr * 128 + rr * 16 + lq * 4 + i;
                const long col = colBase + wc * 64 + cc * 16 + lm;
                if constexpr (GRAN) {
                    // f16 partial into dead high granule of this row's slot
                    Chi[row * 16384 + 8192 + z * 1024 + col] =
                        (_Float16)acc[rr][cc][i];
                } else if constexpr (SPLIT_OUT) {
                    float v = acc[rr][cc][i];
                    _Float16 h = (_Float16)v;
                    Chi[row * ldc + col] = h;
                    Clo[row * ldc + col] = (_Float16)(v - (float)h);
                } else {
                    C[row * ldc + col] = acc[rr][cc][i];
                }
            }
}

// ---------------------------------------------------------------- softmax
// One block per row (8192 fp32). Whole row into registers (paired float4 =
// 32 B/lane contiguous), reduce max and sum(exp), write P f16 as 16 B
// chunks (aliases the fp32 row in-place: all reads complete before the
// first barrier, writes after the last). Scale 1/32 folded in.
__global__ __launch_bounds__(256) void softmax_rows(const float* __restrict__ S,
                                                    _Float16* __restrict__ P,
                                                    long ldp, int N) {
    const int row = blockIdx.x;
    const int t = threadIdx.x;
    const float4* rowp = (const float4*)(S + (size_t)row * N);
    float4 v[8];
    float mx = -3.4e38f;
#pragma unroll
    for (int g = 0; g < 4; ++g) {
        v[2 * g]     = rowp[2 * t + 512 * g];
        v[2 * g + 1] = rowp[2 * t + 512 * g + 1];
    }
#pragma unroll
    for (int i = 0; i < 8; ++i)
        mx = fmaxf(mx, fmaxf(fmaxf(v[i].x, v[i].y), fmaxf(v[i].z, v[i].w)));
    __shared__ float red[8];
#pragma unroll
    for (int off = 32; off >= 1; off >>= 1) mx = fmaxf(mx, __shfl_xor(mx, off));
    if ((t & 63) == 0) red[t >> 6] = mx;
    __syncthreads();
    mx = fmaxf(fmaxf(red[0], red[1]), fmaxf(red[2], red[3]));

    float sum = 0.0f;
#pragma unroll
    for (int i = 0; i < 8; ++i) {
        v[i].x = __expf((v[i].x - mx) * 0.03125f);
        v[i].y = __expf((v[i].y - mx) * 0.03125f);
        v[i].z = __expf((v[i].z - mx) * 0.03125f);
        v[i].w = __expf((v[i].w - mx) * 0.03125f);
        sum += (v[i].x + v[i].y) + (v[i].z + v[i].w);
    }
#pragma unroll
    for (int off = 32; off >= 1; off >>= 1) sum += __shfl_xor(sum, off);
    if ((t & 63) == 0) red[4 + (t >> 6)] = sum;
    __syncthreads();
    float inv = 1.0f / (red[4] + red[5] + red[6] + red[7]);

    f16x8* prow = (f16x8*)(P + (size_t)row * ldp);
#pragma unroll
    for (int g = 0; g < 4; ++g) {
        float4 a = v[2 * g], b = v[2 * g + 1];
        f16x8 o;
        o[0] = (_Float16)(a.x * inv); o[1] = (_Float16)(a.y * inv);
        o[2] = (_Float16)(a.z * inv); o[3] = (_Float16)(a.w * inv);
        o[4] = (_Float16)(b.x * inv); o[5] = (_Float16)(b.y * inv);
        o[6] = (_Float16)(b.z * inv); o[7] = (_Float16)(b.w * inv);
        prow[t + 256 * g] = o;
    }
}

// ---------------------------------------------------------------- launch
extern "C" void kernel_launch(void* const* d_in, const int* in_sizes, int n_in,
                              void* d_out, int out_size, void* d_ws, size_t ws_size,
                              hipStream_t stream) {
    const float* X  = (const float*)d_in[0];  // [8192,1024]
    const float* Wq = (const float*)d_in[1];  // [1024,1024]
    const float* Wk = (const float*)d_in[2];  // [1024,1024]
    float* out = (float*)d_out;               // [8192,1024]

    const long Nt = 8192, D = 1024;
    char* ws = (char*)d_ws;
    const size_t MB = 1024ull * 1024ull;

    // Persistent region (80 MB):
    _Float16* XT  = (_Float16*)(ws + 0);        // 16 MB [1024][8192] = X^T f16
    _Float16* Qhi = (_Float16*)(ws + 16 * MB);  // 16 MB
    _Float16* Qlo = (_Float16*)(ws + 32 * MB);
    _Float16* Khi = (_Float16*)(ws + 48 * MB);
    _Float16* Klo = (_Float16*)(ws + 64 * MB);
    // Transient (dead after projections; Sc aliases them):
    _Float16* Xhi   = (_Float16*)(ws + 80 * MB);   // 16 MB
    _Float16* Xlo   = (_Float16*)(ws + 96 * MB);   // 16 MB
    _Float16* WqThi = (_Float16*)(ws + 112 * MB);  // 2 MB each, Wq/Wk adjacent
    _Float16* WqTlo = (_Float16*)(ws + 114 * MB);
    _Float16* WkThi = (_Float16*)(ws + 116 * MB);
    _Float16* WkTlo = (_Float16*)(ws + 118 * MB);

    // Chunk scratch: S fp32 rows (32 KB each). After softmax, each row slot
    // = [P f16 16 KB][dead 16 KB used for PV split-K f16 partials].
    const size_t rowBytes = (size_t)Nt * 4;  // 32 KB per S row
    float* Sc = (float*)(ws + 80 * MB);
    size_t avail = ws_size > 80 * MB ? ws_size - 80 * MB : 0;
    long chunk = (long)((avail / rowBytes / 256) * 256);
    if (chunk < 256) chunk = 256;   // smaller ws cannot work anyway
    if (chunk > Nt) chunk = Nt;
    // even-size chunks (avoid a tiny low-occupancy tail chunk)
    {
        long nch = (Nt + chunk - 1) / chunk;
        chunk = (((Nt + nch - 1) / nch) + 255) / 256 * 256;
    }

    // 1. prep: one pass over X -> Xhi,Xlo,XT; transpose+split weights
    prep_x<<<dim3(32, 256), dim3(32, 8), 0, stream>>>(X, Xhi, Xlo, XT,
                                                      (int)Nt, (int)D);
    transpose_split<<<dim3(32, 32), dim3(32, 8), 0, stream>>>(Wq, WqThi, WqTlo,
                                                              (int)D, (int)D);
    transpose_split<<<dim3(32, 32), dim3(32, 8), 0, stream>>>(Wk, WkThi, WkTlo,
                                                              (int)D, (int)D);

    // 2. fused Q+K projections (3-term split), z=0 -> Q, z=1 -> K.
    //    grid 32x4x2 = 256 blocks: exactly 1/CU.
    gemm_p4<3, 32, 1, 1, 0><<<dim3(32 * 4, 1, 2), 512, 0, stream>>>(
        Xhi, Xlo, WqThi, WqTlo, nullptr, Qhi, Qlo,
        D, D, D, (int)D, 32, 4,
        0, (long)(4 * MB / 2), (long)(32 * MB / 2));

    // 3. chunks: S = Q@K^T (3-term, fp32) -> softmax in place (P f16 in
    //    low granules) -> PV split-K=8 full-chip (f16 partials in high
    //    granules) -> add_gran reduce into out.
    long done = 0;
    while (done < Nt) {
        long cur = Nt - done < chunk ? Nt - done : chunk;
        int nrb = (int)(cur / 256), ncb = (int)(Nt / 256);
        // SWAP=0: concurrent blocks within an XCD share B (K) panels
        // (~4 MB = L2-resident); Q streams via L3. A/B vs R16's SWAP=1
        // (FETCH 270 MB = L2 thrash on 32 distinct K panels).
        gemm_p4<3, 32, 0, 0, 0><<<dim3(nrb * ncb, 1, 1), 512, 0, stream>>>(
            Qhi + done * D, Qlo + done * D, Khi, Klo, Sc, nullptr, nullptr,
            D, D, Nt, (int)D, nrb, ncb, 0, 0, 0);
        softmax_rows<<<(int)cur, 256, 0, stream>>>(Sc, (_Float16*)Sc,
                                                   2 * Nt, (int)Nt);
        // PV: A = P (sparse rows, lda = 2*Nt halves), B = XT, split-K=8
        // (z offsets k by 1024 in both A cols and XT cols). Grid
        // (cur/256) x 4 x 8 -> full chip. SWAP=1 (R8/R9 measured best).
        gemm_p4<1, 64, 1, 0, 1><<<dim3(nrb * 4, 1, 8), 512, 0, stream>>>(
            (const _Float16*)Sc, nullptr, XT, nullptr,
            nullptr, (_Float16*)Sc, nullptr,
            2 * Nt, Nt, D, (int)(Nt / 8), nrb, 4,
            Nt / 8, Nt / 8, 0);
        add_gran<<<(int)cur, 128, 0, stream>>>((const _Float16*)Sc,
                                               out + done * D);
        done += cur;
    }
}